// Round 3
// baseline (197.213 us; speedup 1.0000x reference)
//
#include <hip/hip_runtime.h>
#include <math.h>

#define BB 8
#define NN 2048
#define DD 128
#define HH 8

typedef _Float16 v4h __attribute__((ext_vector_type(4)));
typedef _Float16 v8h __attribute__((ext_vector_type(8)));
typedef float    v4f __attribute__((ext_vector_type(4)));
typedef float    v16f __attribute__((ext_vector_type(16)));

__device__ __forceinline__ v4f zero4() { v4f z = {0.f, 0.f, 0.f, 0.f}; return z; }
__device__ __forceinline__ v16f zero16() {
    v16f z;
    #pragma unroll
    for (int i = 0; i < 16; ++i) z[i] = 0.f;
    return z;
}

__device__ __forceinline__ v4f mfma16(v4h a, v4h b, v4f c) {
    return __builtin_amdgcn_mfma_f32_16x16x16f16(a, b, c, 0, 0, 0);
}
__device__ __forceinline__ v16f mfma32(v8h a, v8h b, v16f c) {
    return __builtin_amdgcn_mfma_f32_32x32x16_f16(a, b, c, 0, 0, 0);
}

__device__ __forceinline__ float fexp2(float x) {
#if __has_builtin(__builtin_amdgcn_exp2f)
    return __builtin_amdgcn_exp2f(x);          // v_exp_f32 (2^x)
#else
    return __expf(x * 0.69314718055994531f);
#endif
}

// LOGIT_SCALE = ln400/ln50/4 = 0.38288787333
// QSCALE = 2*LOGIT_SCALE*log2(e): folded into Q rope tables so S = log2(e^{2z})
#define QSCALE 1.10478088f
#define C1F 14.426950408889634f   /* 10*log2e */
#define C2F 28.853900817779268f   /* 20*log2e */

// ---------------- prep: weights fp32->fp16, RoPE/xpos tables (all fp32) ----------------
__global__ __launch_bounds__(256) void prep_kernel(
    const float* __restrict__ Wq, const float* __restrict__ Wk,
    const float* __restrict__ Wv, const float* __restrict__ Wo,
    _Float16* __restrict__ WH, _Float16* __restrict__ WoH,
    float* __restrict__ rtab)
{
    int tid = blockIdx.x * 256 + threadIdx.x;        // 65536 threads
    int m = tid >> 14, i = tid & 16383;
    const float* src = (m == 0) ? Wq : (m == 1) ? Wk : (m == 2) ? Wv : Wo;
    float wv = src[i];
    if (m < 3) WH[m * 16384 + i] = (_Float16)wv;
    else       WoH[i] = (_Float16)wv;

    if (tid < NN * 16) {
        int t = tid >> 4, hd = tid & 15, j = hd >> 1;
        // invf = 10000^(-j/8) = 10^(-j/2): exact constants
        const float invf_tab[8] = {1.f, 0.31622776601683794f, 0.1f, 0.031622776601683791f,
                                   0.01f, 0.0031622776601683794f, 0.001f, 0.00031622776601683794f};
        float freq = (float)t * invf_tab[j];
        float c = cosf(freq), s = sinf(freq);    // fp32, accurate arg reduction
        float scf = ((float)(2 * j) + 6.4f) / 22.4f;
        float pw  = ((float)t - 1024.0f) / 512.0f;
        float scl = exp2f(pw * log2f(scf));
        rtab[0 * NN * 16 + tid] = c * scl * QSCALE;   // Q cos*scale (pre-scaled)
        rtab[1 * NN * 16 + tid] = s * scl * QSCALE;   // Q sin*scale (pre-scaled)
        float is = 1.0f / scl;
        rtab[2 * NN * 16 + tid] = c * is;             // K cos/scale
        rtab[3 * NN * 16 + tid] = s * is;             // K sin/scale
    }
}

// ---------------- fused QKV projection + RoPE (one m per blockIdx.y) ----------------
__global__ __launch_bounds__(256) void proj_rope_kernel(
    const float* __restrict__ q, const float* __restrict__ k, const float* __restrict__ v,
    const _Float16* __restrict__ WH, const float* __restrict__ rtab,
    _Float16* __restrict__ Qr, _Float16* __restrict__ Kr, _Float16* __restrict__ VT)
{
    __shared__ __align__(16) _Float16 xb[64][136];
    const int tid = threadIdx.x;
    const int m  = blockIdx.y;
    const int r0 = blockIdx.x * 64;          // 64 token rows per block
    const int b  = r0 >> 11;
    const int n0 = r0 & 2047;

    const float* s = ((m == 0) ? q : (m == 1) ? k : v) + (size_t)r0 * 128;
    #pragma unroll
    for (int i = 0; i < 8; ++i) {
        int u = tid + i * 256;                       // 2048 float4 chunks
        int row = u >> 5, c4 = (u & 31) * 4;
        v4f f = *(const v4f*)(s + row * 128 + c4);
        v4h hv; hv[0]=(_Float16)f[0]; hv[1]=(_Float16)f[1]; hv[2]=(_Float16)f[2]; hv[3]=(_Float16)f[3];
        *(v4h*)&xb[row][c4] = hv;
    }
    __syncthreads();

    const int w = tid >> 6, lane = tid & 63;
    const int l16 = lane & 15, quad = lane >> 4;

    v4h xf[8];
    #pragma unroll
    for (int kt = 0; kt < 8; ++kt)
        xf[kt] = *(const v4h*)&xb[w * 16 + l16][kt * 16 + quad * 4];
    const _Float16* Wm = WH + m * 16384;
    v4f acc[8];
    #pragma unroll
    for (int ct = 0; ct < 8; ++ct) acc[ct] = zero4();
    #pragma unroll
    for (int kt = 0; kt < 8; ++kt) {
        #pragma unroll
        for (int ct = 0; ct < 8; ++ct) {
            v4h wf = *(const v4h*)(Wm + (ct * 16 + l16) * 128 + kt * 16 + quad * 4);
            if (m < 2) acc[ct] = mfma16(wf, xf[kt], acc[ct]);   // D = W * x^T
            else       acc[ct] = mfma16(xf[kt], wf, acc[ct]);   // D = x * W^T
        }
    }
    if (m < 2) {
        const float* tc = rtab + (m == 0 ? 0 : 2 * NN * 16);
        const float* ts = tc + NN * 16;
        const int n = n0 + w * 16 + l16;
        _Float16* dst = (m == 0 ? Qr : Kr);
        #pragma unroll
        for (int ct = 0; ct < 8; ++ct) {
            v4f cs = *(const v4f*)(tc + n * 16 + quad * 4);
            v4f sn = *(const v4f*)(ts + n * 16 + quad * 4);
            v4f a = acc[ct];
            v4f rot; rot[0] = -a[1]; rot[1] = a[0]; rot[2] = -a[3]; rot[3] = a[2];
            v4h o;
            #pragma unroll
            for (int r = 0; r < 4; ++r) o[r] = (_Float16)(a[r] * cs[r] + rot[r] * sn[r]);
            *(v4h*)(dst + ((size_t)(b * 8 + ct) * NN + n) * 16 + quad * 4) = o;
        }
    } else {
        #pragma unroll
        for (int ct = 0; ct < 8; ++ct) {
            v4f a = acc[ct];
            v4h o;
            #pragma unroll
            for (int r = 0; r < 4; ++r) o[r] = (_Float16)a[r];
            *(v4h*)(VT + ((size_t)(b * 8 + ct) * 16 + l16) * NN + n0 + w * 16 + quad * 4) = o;
        }
    }
}

// ---------------- fused attention (32x32 MFMA, in-block split-K) ----------------
// 512 threads = 8 waves. Waves 0-3 (g=0): k in [0,1024); waves 4-7 (g=1): k in
// [1024,2048) -- same 128 q-rows, private staging per group. Grid 1024 x 8 waves
// = 8192 waves = 100% nominal occupancy (4 blocks/CU, LDS 30720B -> fits).
// Partials combine exactly in LDS (p <= e^10, no max-rescale): upper waves dump
// acc+rowsum, lower waves add, normalize, transpose, store.
__global__ __launch_bounds__(512, 8) void attn_kernel(
    const _Float16* __restrict__ Qr, const _Float16* __restrict__ Kr,
    const _Float16* __restrict__ VT, const unsigned char* __restrict__ mask,
    _Float16* __restrict__ Obuf)
{
    __shared__ __align__(16) char smem[30720];

    const int tid = threadIdx.x;
    const int g  = tid >> 8;                     // k-half group
    const int ts = tid & 255;                    // thread-in-group
    char* halfb = smem + g * 15360;
    _Float16* Kt = (_Float16*)halfb;             // [128][24] halfs
    _Float16* Ve = (_Float16*)(halfb + 6144);    // [32][136] halfs (rows 0-15 V, 16-31 ones)
    float*    av = (float*)(halfb + 14848);      // [128] mask addend

    const int bh = blockIdx.x >> 4;              // 64 (b,h)
    const int qt = blockIdx.x & 15;              // 16 q-tiles of 128
    const int b = bh >> 3, h = bh & 7;
    const int q0 = qt * 128;
    const int w = tid >> 6, lane = tid & 63;
    const int wq = w & 3;                        // q-subtile within block
    const int l32 = lane & 31, hi = lane >> 5;

    // Q fragment (B-operand): col=q=l32, k(hd)=hi*8+j
    const int qrow = q0 + wq * 32 + l32;
    v8h qf = *(const v8h*)(Qr + ((size_t)bh * NN + qrow) * 16 + hi * 8);

    // ones rows of Ve (written once per group; untouched by per-iter staging)
    {
        v8h one8;
        #pragma unroll
        for (int i = 0; i < 8; ++i) one8[i] = (_Float16)1.f;
        *(v8h*)(Ve + (16 + (ts >> 4)) * 136 + (ts & 15) * 8) = one8;
    }

    v16f acc = zero16();

    const int krow = ts >> 1, kpar = ts & 1;     // K staging: 128 rows x 2 halves
    const int vhd = ts >> 4, vg = ts & 15;       // V staging: 16 hd x 16 k-groups of 8
    const int kbase = g * 1024;

    for (int it = 0; it < 8; ++it) {
        const int k0 = kbase + it * 128;
        __syncthreads();
        // K tile [128][16] -> Kt (row stride 24 halfs)
        v8h kv = *(const v8h*)(Kr + ((size_t)bh * NN + k0 + krow) * 16 + kpar * 8);
        *(v8h*)(Kt + krow * 24 + kpar * 8) = kv;
        // V tile with slot permutation: within each 16-k group, slots [4..7]<->[8..11]
        v8h vv = *(const v8h*)(VT + ((size_t)bh * 16 + vhd) * NN + k0 + vg * 8);
        {
            _Float16* vb = Ve + vhd * 136 + (vg >> 1) * 16 + (vg & 1) * 4;
            v4h lo4, hi4;
            lo4[0]=vv[0]; lo4[1]=vv[1]; lo4[2]=vv[2]; lo4[3]=vv[3];
            hi4[0]=vv[4]; hi4[1]=vv[5]; hi4[2]=vv[6]; hi4[3]=vv[7];
            *(v4h*)(vb)     = lo4;     // logical k g*8+0..3
            *(v4h*)(vb + 8) = hi4;     // logical k g*8+4..7 -> swapped slot group
        }
        if (ts < 128) av[ts] = mask[b * NN + k0 + ts] ? -1e30f : C1F;
        __syncthreads();

        #pragma unroll
        for (int kc = 0; kc < 4; ++kc) {
            // A = K rows (row=k-pos=l32 within chunk, k-dim=hd=hi*8+j)
            v8h kf = *(const v8h*)(Kt + (kc * 32 + l32) * 24 + hi * 8);
            v16f sv = mfma32(kf, qf, zero16());   // S^T: col=q=l32, row k=(r&3)+8*(r>>2)+4*hi

            v4f ad[4];
            #pragma unroll
            for (int gg = 0; gg < 4; ++gg)
                ad[gg] = *(const v4f*)(av + kc * 32 + gg * 8 + hi * 4);

            float p[16];
            #pragma unroll
            for (int r = 0; r < 16; ++r) {
                float u  = fexp2(sv[r]);                           // e^{2z}
                float rc = __builtin_amdgcn_rcpf(u + 1.f);         // inf-safe
                p[r] = fexp2(__builtin_fmaf(rc, -C2F, ad[r >> 2][r & 3]));
            }

            #pragma unroll
            for (int c2 = 0; c2 < 2; ++c2) {
                v8h pa;
                #pragma unroll
                for (int j = 0; j < 8; ++j) pa[j] = (_Float16)p[c2 * 8 + j];
                v8h vf = *(const v8h*)(Ve + l32 * 136 + (kc * 2 + c2) * 16 + hi * 8);
                acc = mfma32(pa, vf, acc);         // rows=q, cols: 0-15 O^T, 16-31 rowsum
            }
        }
    }

    // ---- combine + epilogue ----
    // row sums live in partner lanes (col >= 16); same reg index
    float rs[16];
    #pragma unroll
    for (int r = 0; r < 16; ++r) rs[r] = __shfl_xor(acc[r], 16, 64);

    __syncthreads();                               // all staging reads done: safe to alias
    float* pair = (float*)smem;                    // [4 wq][32 q][17] f32 = 8704 B
    if (g == 1 && !(lane & 16)) {
        int j = lane & 15;
        float* pb = pair + wq * 544;
        #pragma unroll
        for (int r = 0; r < 16; ++r) {
            int qr = (r & 3) + 8 * (r >> 2) + 4 * hi;
            pb[qr * 17 + j] = acc[r];
            if (j == 0) pb[qr * 17 + 16] = rs[r];
        }
    }
    __syncthreads();
    if (g == 0) {
        _Float16* myOt = (_Float16*)(smem + 8704) + wq * 768;   // [32 q][24] halfs
        if (!(lane & 16)) {
            int j = lane & 15;
            const float* pb = pair + wq * 544;
            #pragma unroll
            for (int r = 0; r < 16; ++r) {
                int qr = (r & 3) + 8 * (r >> 2) + 4 * hi;
                float tot = acc[r] + pb[qr * 17 + j];
                float rst = rs[r]  + pb[qr * 17 + 16];
                myOt[qr * 24 + j] = (_Float16)(tot * __builtin_amdgcn_rcpf(rst));
            }
        }
        asm volatile("s_waitcnt lgkmcnt(0)" ::: "memory"); // wave-private region
        v8h ov = *(const v8h*)(myOt + (lane >> 1) * 24 + (lane & 1) * 8);
        *(v8h*)(Obuf + ((size_t)(b * NN + q0 + wq * 32 + (lane >> 1)) * 128) + h * 16 + (lane & 1) * 8) = ov;
    }
}

// ---------------- output projection: out = O @ Wout^T (fp32 out), col-split grid.y ----------------
__global__ __launch_bounds__(256) void outproj_kernel(
    const _Float16* __restrict__ Obuf, const _Float16* __restrict__ WoH,
    float* __restrict__ out)
{
    __shared__ __align__(16) _Float16 ob[64][136];
    const int tid = threadIdx.x;
    const int r0 = blockIdx.x * 64;
    const int ct0 = blockIdx.y * 2;                 // 4-way col split: 32 cols/block
    #pragma unroll
    for (int i = 0; i < 8; ++i) {
        int u = tid + i * 256;
        int row = u >> 5, c4 = (u & 31) * 4;
        *(v4h*)&ob[row][c4] = *(const v4h*)(Obuf + (size_t)(r0 + row) * 128 + c4);
    }
    __syncthreads();
    const int w = tid >> 6, lane = tid & 63;
    const int l16 = lane & 15, quad = lane >> 4;
    v4h af[8];
    #pragma unroll
    for (int kt = 0; kt < 8; ++kt)
        af[kt] = *(const v4h*)&ob[w * 16 + l16][kt * 16 + quad * 4];
    v4f acc[2];
    #pragma unroll
    for (int c = 0; c < 2; ++c) acc[c] = zero4();
    #pragma unroll
    for (int kt = 0; kt < 8; ++kt)
        #pragma unroll
        for (int c = 0; c < 2; ++c) {
            v4h wf = *(const v4h*)(WoH + ((ct0 + c) * 16 + l16) * 128 + kt * 16 + quad * 4);
            acc[c] = mfma16(af[kt], wf, acc[c]);
        }
    #pragma unroll
    for (int c = 0; c < 2; ++c)
        #pragma unroll
        for (int r = 0; r < 4; ++r)
            out[(size_t)(r0 + w * 16 + quad * 4 + r) * 128 + (ct0 + c) * 16 + l16] = acc[c][r];
}

extern "C" void kernel_launch(void* const* d_in, const int* in_sizes, int n_in,
                              void* d_out, int out_size, void* d_ws, size_t ws_size,
                              hipStream_t stream)
{
    const float* q  = (const float*)d_in[0];
    const float* k  = (const float*)d_in[1];
    const float* v  = (const float*)d_in[2];
    const float* Wq = (const float*)d_in[3];
    const float* Wk = (const float*)d_in[4];
    const float* Wv = (const float*)d_in[5];
    const float* Wo = (const float*)d_in[6];
    const unsigned char* mask = (const unsigned char*)d_in[7];
    float* out = (float*)d_out;

    char* ws = (char*)d_ws;
    _Float16* WH   = (_Float16*)(ws);                 //  96 KB  (Wq,Wk,Wv fp16)
    _Float16* WoH  = (_Float16*)(ws + 98304);         //  32 KB
    float*    rtab = (float*)(ws + 131072);           // 512 KB  (4 rope tables)
    _Float16* Qr   = (_Float16*)(ws + 655360);        //   4 MB  (B,H,N,16)
    _Float16* Kr   = (_Float16*)(ws + 4849664);       //   4 MB
    _Float16* VTd  = (_Float16*)(ws + 9043968);       //   4 MB  (B,H,16,N)
    _Float16* Obuf = (_Float16*)(ws + 13238272);      //   4 MB  (B*N,128)

    prep_kernel<<<256, 256, 0, stream>>>(Wq, Wk, Wv, Wo, WH, WoH, rtab);
    proj_rope_kernel<<<dim3(256, 3), 256, 0, stream>>>(q, k, v, WH, rtab, Qr, Kr, VTd);
    attn_kernel<<<1024, 512, 0, stream>>>(Qr, Kr, VTd, mask, Obuf);
    outproj_kernel<<<dim3(256, 4), 256, 0, stream>>>(Obuf, WoH, out);
}

// Round 4
// 195.252 us; speedup vs baseline: 1.0100x; 1.0100x over previous
//
#include <hip/hip_runtime.h>
#include <math.h>

#define BB 8
#define NN 2048
#define DD 128
#define HH 8

typedef _Float16 v4h __attribute__((ext_vector_type(4)));
typedef _Float16 v8h __attribute__((ext_vector_type(8)));
typedef float    v4f __attribute__((ext_vector_type(4)));
typedef float    v16f __attribute__((ext_vector_type(16)));

__device__ __forceinline__ v4f zero4() { v4f z = {0.f, 0.f, 0.f, 0.f}; return z; }
__device__ __forceinline__ v16f zero16() {
    v16f z;
    #pragma unroll
    for (int i = 0; i < 16; ++i) z[i] = 0.f;
    return z;
}

__device__ __forceinline__ v4f mfma16(v4h a, v4h b, v4f c) {
    return __builtin_amdgcn_mfma_f32_16x16x16f16(a, b, c, 0, 0, 0);
}
__device__ __forceinline__ v16f mfma32(v8h a, v8h b, v16f c) {
    return __builtin_amdgcn_mfma_f32_32x32x16_f16(a, b, c, 0, 0, 0);
}

__device__ __forceinline__ float fexp2(float x) {
#if __has_builtin(__builtin_amdgcn_exp2f)
    return __builtin_amdgcn_exp2f(x);          // v_exp_f32 (2^x)
#else
    return __expf(x * 0.69314718055994531f);
#endif
}

// LOGIT_SCALE = ln400/ln50/4 = 0.38288787333
// QSCALE = 2*LOGIT_SCALE*log2(e): folded into Q rope tables so S = log2(e^{2z})
#define QSCALE 1.10478088f
#define C1F 14.426950408889634f   /* 10*log2e */
#define C2F 28.853900817779268f   /* 20*log2e */

// ---------------- prep: weights fp32->fp16, RoPE/xpos tables (all fp32) ----------------
__global__ __launch_bounds__(256) void prep_kernel(
    const float* __restrict__ Wq, const float* __restrict__ Wk,
    const float* __restrict__ Wv, const float* __restrict__ Wo,
    _Float16* __restrict__ WH, _Float16* __restrict__ WoH,
    float* __restrict__ rtab)
{
    int tid = blockIdx.x * 256 + threadIdx.x;        // 65536 threads
    int m = tid >> 14, i = tid & 16383;
    const float* src = (m == 0) ? Wq : (m == 1) ? Wk : (m == 2) ? Wv : Wo;
    float wv = src[i];
    if (m < 3) WH[m * 16384 + i] = (_Float16)wv;
    else       WoH[i] = (_Float16)wv;

    if (tid < NN * 16) {
        int t = tid >> 4, hd = tid & 15, j = hd >> 1;
        // invf = 10000^(-j/8) = 10^(-j/2): exact constants
        const float invf_tab[8] = {1.f, 0.31622776601683794f, 0.1f, 0.031622776601683791f,
                                   0.01f, 0.0031622776601683794f, 0.001f, 0.00031622776601683794f};
        float freq = (float)t * invf_tab[j];
        float c = cosf(freq), s = sinf(freq);    // fp32, accurate arg reduction
        float scf = ((float)(2 * j) + 6.4f) / 22.4f;
        float pw  = ((float)t - 1024.0f) / 512.0f;
        float scl = exp2f(pw * log2f(scf));
        rtab[0 * NN * 16 + tid] = c * scl * QSCALE;   // Q cos*scale (pre-scaled)
        rtab[1 * NN * 16 + tid] = s * scl * QSCALE;   // Q sin*scale (pre-scaled)
        float is = 1.0f / scl;
        rtab[2 * NN * 16 + tid] = c * is;             // K cos/scale
        rtab[3 * NN * 16 + tid] = s * is;             // K sin/scale
    }
}

// ---------------- fused QKV projection + RoPE (one m per blockIdx.y) ----------------
__global__ __launch_bounds__(256) void proj_rope_kernel(
    const float* __restrict__ q, const float* __restrict__ k, const float* __restrict__ v,
    const _Float16* __restrict__ WH, const float* __restrict__ rtab,
    _Float16* __restrict__ Qr, _Float16* __restrict__ Kr, _Float16* __restrict__ VT)
{
    __shared__ __align__(16) _Float16 xb[64][136];
    const int tid = threadIdx.x;
    const int m  = blockIdx.y;
    const int r0 = blockIdx.x * 64;          // 64 token rows per block
    const int b  = r0 >> 11;
    const int n0 = r0 & 2047;

    const float* s = ((m == 0) ? q : (m == 1) ? k : v) + (size_t)r0 * 128;
    #pragma unroll
    for (int i = 0; i < 8; ++i) {
        int u = tid + i * 256;                       // 2048 float4 chunks
        int row = u >> 5, c4 = (u & 31) * 4;
        v4f f = *(const v4f*)(s + row * 128 + c4);
        v4h hv; hv[0]=(_Float16)f[0]; hv[1]=(_Float16)f[1]; hv[2]=(_Float16)f[2]; hv[3]=(_Float16)f[3];
        *(v4h*)&xb[row][c4] = hv;
    }
    __syncthreads();

    const int w = tid >> 6, lane = tid & 63;
    const int l16 = lane & 15, quad = lane >> 4;

    v4h xf[8];
    #pragma unroll
    for (int kt = 0; kt < 8; ++kt)
        xf[kt] = *(const v4h*)&xb[w * 16 + l16][kt * 16 + quad * 4];
    const _Float16* Wm = WH + m * 16384;
    v4f acc[8];
    #pragma unroll
    for (int ct = 0; ct < 8; ++ct) acc[ct] = zero4();
    #pragma unroll
    for (int kt = 0; kt < 8; ++kt) {
        #pragma unroll
        for (int ct = 0; ct < 8; ++ct) {
            v4h wf = *(const v4h*)(Wm + (ct * 16 + l16) * 128 + kt * 16 + quad * 4);
            if (m < 2) acc[ct] = mfma16(wf, xf[kt], acc[ct]);   // D = W * x^T
            else       acc[ct] = mfma16(xf[kt], wf, acc[ct]);   // D = x * W^T
        }
    }
    if (m < 2) {
        const float* tc = rtab + (m == 0 ? 0 : 2 * NN * 16);
        const float* ts = tc + NN * 16;
        const int n = n0 + w * 16 + l16;
        _Float16* dst = (m == 0 ? Qr : Kr);
        #pragma unroll
        for (int ct = 0; ct < 8; ++ct) {
            v4f cs = *(const v4f*)(tc + n * 16 + quad * 4);
            v4f sn = *(const v4f*)(ts + n * 16 + quad * 4);
            v4f a = acc[ct];
            v4f rot; rot[0] = -a[1]; rot[1] = a[0]; rot[2] = -a[3]; rot[3] = a[2];
            v4h o;
            #pragma unroll
            for (int r = 0; r < 4; ++r) o[r] = (_Float16)(a[r] * cs[r] + rot[r] * sn[r]);
            *(v4h*)(dst + ((size_t)(b * 8 + ct) * NN + n) * 16 + quad * 4) = o;
        }
    } else {
        #pragma unroll
        for (int ct = 0; ct < 8; ++ct) {
            v4f a = acc[ct];
            v4h o;
            #pragma unroll
            for (int r = 0; r < 4; ++r) o[r] = (_Float16)a[r];
            *(v4h*)(VT + ((size_t)(b * 8 + ct) * 16 + l16) * NN + n0 + w * 16 + quad * 4) = o;
        }
    }
}

// ---------------- fused attention (32x32 MFMA + register-prefetch pipeline) ----------------
// R2 structure (256 thr, 4 waves, full K per block) + T14 async-stage split:
// prologue loads tile 0 to regs; each iter: barrier -> ds_write(cur) ->
// issue global loads(next) -> barrier -> compute(cur). Next-tile HBM/L2
// latency hides under the ~2.2k-cycle transform. launch_bounds (256,4):
// 128 VGPR budget for prefetch regs + 16-wide transform ILP.
__global__ __launch_bounds__(256, 4) void attn_kernel(
    const _Float16* __restrict__ Qr, const _Float16* __restrict__ Kr,
    const _Float16* __restrict__ VT, const unsigned char* __restrict__ mask,
    _Float16* __restrict__ Obuf)
{
    __shared__ __align__(16) char smem[15360];
    _Float16* Kt = (_Float16*)smem;              // [128][24] halfs (row stride 48 B)
    _Float16* Ve = (_Float16*)(smem + 6144);     // [32][136] halfs (rows 0-15 V, 16-31 ones)
    float*    av = (float*)(smem + 14848);       // [128] mask addend

    const int tid = threadIdx.x;
    const int bh = blockIdx.x >> 4;              // 64 (b,h)
    const int qt = blockIdx.x & 15;              // 16 q-tiles of 128
    const int b = bh >> 3, h = bh & 7;
    const int q0 = qt * 128;
    const int w = tid >> 6, lane = tid & 63;
    const int l32 = lane & 31, hi = lane >> 5;

    // Q fragment (B-operand): col=q=l32, k(hd)=hi*8+j
    const int qrow = q0 + w * 32 + l32;
    v8h qf = *(const v8h*)(Qr + ((size_t)bh * NN + qrow) * 16 + hi * 8);

    // ones rows of Ve (written once; untouched by per-iter staging)
    {
        v8h one8;
        #pragma unroll
        for (int i = 0; i < 8; ++i) one8[i] = (_Float16)1.f;
        *(v8h*)(Ve + (16 + (tid >> 4)) * 136 + (tid & 15) * 8) = one8;
    }

    v16f acc = zero16();

    const int krow = tid >> 1, kpar = tid & 1;   // K staging: 128 rows x 2 halves
    const int vhd = tid >> 4, vg = tid & 15;     // V staging: 16 hd x 16 k-groups of 8
    const _Float16* Kbase = Kr + (size_t)bh * NN * 16;
    const _Float16* Vbase = VT + ((size_t)bh * 16 + vhd) * NN;
    const unsigned char* mbase = mask + b * NN;

    // ---- prologue: prefetch tile 0 into registers ----
    v8h kv = *(const v8h*)(Kbase + (size_t)krow * 16 + kpar * 8);
    v8h vv = *(const v8h*)(Vbase + vg * 8);
    float adv = 0.f;
    if (tid < 128) adv = mbase[tid] ? -1e30f : C1F;

    for (int it = 0; it < 16; ++it) {
        __syncthreads();                         // previous tile's reads complete
        // ---- stage current tile from regs ----
        *(v8h*)(Kt + krow * 24 + kpar * 8) = kv;
        {
            _Float16* vb = Ve + vhd * 136 + (vg >> 1) * 16 + (vg & 1) * 4;
            v4h lo4, hi4;
            lo4[0]=vv[0]; lo4[1]=vv[1]; lo4[2]=vv[2]; lo4[3]=vv[3];
            hi4[0]=vv[4]; hi4[1]=vv[5]; hi4[2]=vv[6]; hi4[3]=vv[7];
            *(v4h*)(vb)     = lo4;     // logical k g*8+0..3
            *(v4h*)(vb + 8) = hi4;     // logical k g*8+4..7 -> swapped slot group
        }
        if (tid < 128) av[tid] = adv;
        // ---- issue next tile's global loads (latency hides under compute) ----
        if (it < 15) {
            const int k0n = (it + 1) * 128;
            kv = *(const v8h*)(Kbase + (size_t)(k0n + krow) * 16 + kpar * 8);
            vv = *(const v8h*)(Vbase + k0n + vg * 8);
            if (tid < 128) adv = mbase[k0n + tid] ? -1e30f : C1F;
        }
        __syncthreads();                         // staging visible

        #pragma unroll
        for (int kc = 0; kc < 4; ++kc) {
            // A = K rows (row=k-pos=l32 within chunk, k-dim=hd=hi*8+j)
            v8h kf = *(const v8h*)(Kt + (kc * 32 + l32) * 24 + hi * 8);
            v16f sv = mfma32(kf, qf, zero16());   // S^T: col=q=l32, row k=(r&3)+8*(r>>2)+4*hi

            v4f ad[4];
            #pragma unroll
            for (int gg = 0; gg < 4; ++gg)
                ad[gg] = *(const v4f*)(av + kc * 32 + gg * 8 + hi * 4);

            float p[16];
            #pragma unroll
            for (int r = 0; r < 16; ++r) {
                float u  = fexp2(sv[r]);                           // e^{2z}
                float rc = __builtin_amdgcn_rcpf(u + 1.f);         // inf-safe
                p[r] = fexp2(__builtin_fmaf(rc, -C2F, ad[r >> 2][r & 3]));
            }

            #pragma unroll
            for (int c2 = 0; c2 < 2; ++c2) {
                v8h pa;
                #pragma unroll
                for (int j = 0; j < 8; ++j) pa[j] = (_Float16)p[c2 * 8 + j];
                v8h vf = *(const v8h*)(Ve + l32 * 136 + (kc * 2 + c2) * 16 + hi * 8);
                acc = mfma32(pa, vf, acc);         // rows=q, cols: 0-15 O^T, 16-31 rowsum
            }
        }
    }

    // ---- epilogue ----
    // row sums live in partner lanes (col >= 16); same reg index
    float rs[16];
    #pragma unroll
    for (int r = 0; r < 16; ++r) rs[r] = __shfl_xor(acc[r], 16, 64);

    __syncthreads();                                   // all K-tile reads done: safe to alias
    _Float16* myOt = (_Float16*)smem + w * 768;        // per-wave [32 q][24] halfs over Kt
    if (!(lane & 16)) {                                // lanes holding O columns
        int j = lane & 15;                             // hd
        #pragma unroll
        for (int r = 0; r < 16; ++r) {
            int qr = (r & 3) + 8 * (r >> 2) + 4 * hi;  // q-row within wave tile
            myOt[qr * 24 + j] = (_Float16)(acc[r] * __builtin_amdgcn_rcpf(rs[r]));
        }
    }
    asm volatile("s_waitcnt lgkmcnt(0)" ::: "memory"); // wave-private region: no barrier needed
    v8h ov = *(const v8h*)(myOt + (lane >> 1) * 24 + (lane & 1) * 8);
    *(v8h*)(Obuf + ((size_t)(b * NN + q0 + w * 32 + (lane >> 1)) * 128) + h * 16 + (lane & 1) * 8) = ov;
}

// ---------------- output projection: out = O @ Wout^T (fp32 out), col-split grid.y ----------------
__global__ __launch_bounds__(256) void outproj_kernel(
    const _Float16* __restrict__ Obuf, const _Float16* __restrict__ WoH,
    float* __restrict__ out)
{
    __shared__ __align__(16) _Float16 ob[64][136];
    const int tid = threadIdx.x;
    const int r0 = blockIdx.x * 64;
    const int ct0 = blockIdx.y * 2;                 // 4-way col split: 32 cols/block
    #pragma unroll
    for (int i = 0; i < 8; ++i) {
        int u = tid + i * 256;
        int row = u >> 5, c4 = (u & 31) * 4;
        *(v4h*)&ob[row][c4] = *(const v4h*)(Obuf + (size_t)(r0 + row) * 128 + c4);
    }
    __syncthreads();
    const int w = tid >> 6, lane = tid & 63;
    const int l16 = lane & 15, quad = lane >> 4;
    v4h af[8];
    #pragma unroll
    for (int kt = 0; kt < 8; ++kt)
        af[kt] = *(const v4h*)&ob[w * 16 + l16][kt * 16 + quad * 4];
    v4f acc[2];
    #pragma unroll
    for (int c = 0; c < 2; ++c) acc[c] = zero4();
    #pragma unroll
    for (int kt = 0; kt < 8; ++kt)
        #pragma unroll
        for (int c = 0; c < 2; ++c) {
            v4h wf = *(const v4h*)(WoH + ((ct0 + c) * 16 + l16) * 128 + kt * 16 + quad * 4);
            acc[c] = mfma16(af[kt], wf, acc[c]);
        }
    #pragma unroll
    for (int c = 0; c < 2; ++c)
        #pragma unroll
        for (int r = 0; r < 4; ++r)
            out[(size_t)(r0 + w * 16 + quad * 4 + r) * 128 + (ct0 + c) * 16 + l16] = acc[c][r];
}

extern "C" void kernel_launch(void* const* d_in, const int* in_sizes, int n_in,
                              void* d_out, int out_size, void* d_ws, size_t ws_size,
                              hipStream_t stream)
{
    const float* q  = (const float*)d_in[0];
    const float* k  = (const float*)d_in[1];
    const float* v  = (const float*)d_in[2];
    const float* Wq = (const float*)d_in[3];
    const float* Wk = (const float*)d_in[4];
    const float* Wv = (const float*)d_in[5];
    const float* Wo = (const float*)d_in[6];
    const unsigned char* mask = (const unsigned char*)d_in[7];
    float* out = (float*)d_out;

    char* ws = (char*)d_ws;
    _Float16* WH   = (_Float16*)(ws);                 //  96 KB  (Wq,Wk,Wv fp16)
    _Float16* WoH  = (_Float16*)(ws + 98304);         //  32 KB
    float*    rtab = (float*)(ws + 131072);           // 512 KB  (4 rope tables)
    _Float16* Qr   = (_Float16*)(ws + 655360);        //   4 MB  (B,H,N,16)
    _Float16* Kr   = (_Float16*)(ws + 4849664);       //   4 MB
    _Float16* VTd  = (_Float16*)(ws + 9043968);       //   4 MB  (B,H,16,N)
    _Float16* Obuf = (_Float16*)(ws + 13238272);      //   4 MB  (B*N,128)

    prep_kernel<<<256, 256, 0, stream>>>(Wq, Wk, Wv, Wo, WH, WoH, rtab);
    proj_rope_kernel<<<dim3(256, 3), 256, 0, stream>>>(q, k, v, WH, rtab, Qr, Kr, VTd);
    attn_kernel<<<1024, 256, 0, stream>>>(Qr, Kr, VTd, mask, Obuf);
    outproj_kernel<<<dim3(256, 4), 256, 0, stream>>>(Obuf, WoH, out);
}

// Round 5
// 195.134 us; speedup vs baseline: 1.0107x; 1.0006x over previous
//
#include <hip/hip_runtime.h>
#include <math.h>

#define BB 8
#define NN 2048
#define DD 128
#define HH 8

typedef _Float16 v4h __attribute__((ext_vector_type(4)));
typedef _Float16 v8h __attribute__((ext_vector_type(8)));
typedef float    v4f __attribute__((ext_vector_type(4)));
typedef float    v16f __attribute__((ext_vector_type(16)));

__device__ __forceinline__ v4f zero4() { v4f z = {0.f, 0.f, 0.f, 0.f}; return z; }
__device__ __forceinline__ v16f zero16() {
    v16f z;
    #pragma unroll
    for (int i = 0; i < 16; ++i) z[i] = 0.f;
    return z;
}

__device__ __forceinline__ v4f mfma16(v4h a, v4h b, v4f c) {
    return __builtin_amdgcn_mfma_f32_16x16x16f16(a, b, c, 0, 0, 0);
}
__device__ __forceinline__ v16f mfma32(v8h a, v8h b, v16f c) {
    return __builtin_amdgcn_mfma_f32_32x32x16_f16(a, b, c, 0, 0, 0);
}

__device__ __forceinline__ float fexp2(float x) {
#if __has_builtin(__builtin_amdgcn_exp2f)
    return __builtin_amdgcn_exp2f(x);          // v_exp_f32 (2^x)
#else
    return __expf(x * 0.69314718055994531f);
#endif
}

// LOGIT_SCALE = ln400/ln50/4 = 0.38288787333
// QSCALE = 2*LOGIT_SCALE*log2(e): folded into Q rope tables so S = log2(e^{2z})
#define QSCALE 1.10478088f
#define C1F 14.426950408889634f   /* 10*log2e */
#define C2F 28.853900817779268f   /* 20*log2e */

// ---------------- fused QKV projection + RoPE (one m per blockIdx.y) ----------------
// prep_kernel folded in: W read as fp32 + inline cvt (L1/L2-warm), RoPE/xpos
// tables computed per block for its 64 tokens (512 cos/sin pairs, ~2/thread).
__global__ __launch_bounds__(256) void proj_rope_kernel(
    const float* __restrict__ q, const float* __restrict__ k, const float* __restrict__ v,
    const float* __restrict__ Wq, const float* __restrict__ Wk, const float* __restrict__ Wv,
    _Float16* __restrict__ Qr, _Float16* __restrict__ Kr, _Float16* __restrict__ VT)
{
    __shared__ __align__(16) _Float16 xb[64][136];
    __shared__ __align__(16) float ctc[64][16];   // cos coefs (pre-scaled)
    __shared__ __align__(16) float cts[64][16];   // sin coefs (pre-scaled)
    const int tid = threadIdx.x;
    const int m  = blockIdx.y;
    const int r0 = blockIdx.x * 64;          // 64 token rows per block
    const int b  = r0 >> 11;
    const int n0 = r0 & 2047;

    const float* s = ((m == 0) ? q : (m == 1) ? k : v) + (size_t)r0 * 128;
    #pragma unroll
    for (int i = 0; i < 8; ++i) {
        int u = tid + i * 256;                       // 2048 float4 chunks
        int row = u >> 5, c4 = (u & 31) * 4;
        v4f f = *(const v4f*)(s + row * 128 + c4);
        v4h hv; hv[0]=(_Float16)f[0]; hv[1]=(_Float16)f[1]; hv[2]=(_Float16)f[2]; hv[3]=(_Float16)f[3];
        *(v4h*)&xb[row][c4] = hv;
    }

    // in-block RoPE/xpos tables (m<2): 512 (token, j) slots, 2 per thread
    if (m < 2) {
        #pragma unroll
        for (int i = 0; i < 2; ++i) {
            int u2 = tid + i * 256;
            int tl = u2 >> 3, j = u2 & 7;
            // invf = 10^(-j/2) via exact 3-select product (no runtime-indexed array)
            float fa = (j & 4) ? 1e-2f : 1.f;
            float fb = (j & 2) ? 1e-1f : 1.f;
            float fc = (j & 1) ? 0.31622776601683794f : 1.f;
            float invf = fa * fb * fc;
            float t = (float)(n0 + tl);
            float freq = t * invf;
            float c = cosf(freq), si = sinf(freq);   // fp32, accurate arg reduction
            float scf = ((float)(2 * j) + 6.4f) / 22.4f;
            float pw  = (t - 1024.0f) / 512.0f;
            float scl = exp2f(pw * log2f(scf));
            float sc  = (m == 0) ? scl * QSCALE : 1.0f / scl;
            float cc = c * sc, ss = si * sc;
            ctc[tl][2 * j]     = cc;
            ctc[tl][2 * j + 1] = cc;
            cts[tl][2 * j]     = ss;
            cts[tl][2 * j + 1] = ss;
        }
    }
    __syncthreads();

    const int w = tid >> 6, lane = tid & 63;
    const int l16 = lane & 15, quad = lane >> 4;

    v4h xf[8];
    #pragma unroll
    for (int kt = 0; kt < 8; ++kt)
        xf[kt] = *(const v4h*)&xb[w * 16 + l16][kt * 16 + quad * 4];
    const float* Wm = (m == 0) ? Wq : (m == 1) ? Wk : Wv;
    v4f acc[8];
    #pragma unroll
    for (int ct = 0; ct < 8; ++ct) acc[ct] = zero4();
    #pragma unroll
    for (int kt = 0; kt < 8; ++kt) {
        #pragma unroll
        for (int ct = 0; ct < 8; ++ct) {
            v4f wv = *(const v4f*)(Wm + (ct * 16 + l16) * 128 + kt * 16 + quad * 4);
            v4h wf; wf[0]=(_Float16)wv[0]; wf[1]=(_Float16)wv[1]; wf[2]=(_Float16)wv[2]; wf[3]=(_Float16)wv[3];
            if (m < 2) acc[ct] = mfma16(wf, xf[kt], acc[ct]);   // D = W * x^T
            else       acc[ct] = mfma16(xf[kt], wf, acc[ct]);   // D = x * W^T
        }
    }
    if (m < 2) {
        const int tl = w * 16 + l16;
        const int n = n0 + tl;
        _Float16* dst = (m == 0 ? Qr : Kr);
        #pragma unroll
        for (int ct = 0; ct < 8; ++ct) {
            v4f cs = *(const v4f*)&ctc[tl][quad * 4];
            v4f sn = *(const v4f*)&cts[tl][quad * 4];
            v4f a = acc[ct];
            v4f rot; rot[0] = -a[1]; rot[1] = a[0]; rot[2] = -a[3]; rot[3] = a[2];
            v4h o;
            #pragma unroll
            for (int r = 0; r < 4; ++r) o[r] = (_Float16)(a[r] * cs[r] + rot[r] * sn[r]);
            *(v4h*)(dst + ((size_t)(b * 8 + ct) * NN + n) * 16 + quad * 4) = o;
        }
    } else {
        #pragma unroll
        for (int ct = 0; ct < 8; ++ct) {
            v4f a = acc[ct];
            v4h o;
            #pragma unroll
            for (int r = 0; r < 4; ++r) o[r] = (_Float16)a[r];
            *(v4h*)(VT + ((size_t)(b * 8 + ct) * 16 + l16) * NN + n0 + w * 16 + quad * 4) = o;
        }
    }
}

// ---------------- fused attention (32x32 MFMA + reg-prefetch + LDS double-buffer) ----------------
// One barrier per iteration: iter i writes buf(i&1) (vacated by all waves at
// barrier i-1), issues next-tile global loads, barriers, computes buf(i&1).
// Epilogue needs no barrier (writes buf0's Kt area; last compute uses buf1).
__global__ __launch_bounds__(256, 4) void attn_kernel(
    const _Float16* __restrict__ Qr, const _Float16* __restrict__ Kr,
    const _Float16* __restrict__ VT, const unsigned char* __restrict__ mask,
    _Float16* __restrict__ Obuf)
{
    __shared__ __align__(16) char smem[30720];   // 2 x 15360 half-buffers

    const int tid = threadIdx.x;
    const int bh = blockIdx.x >> 4;              // 64 (b,h)
    const int qt = blockIdx.x & 15;              // 16 q-tiles of 128
    const int b = bh >> 3, h = bh & 7;
    const int q0 = qt * 128;
    const int w = tid >> 6, lane = tid & 63;
    const int l32 = lane & 31, hi = lane >> 5;

    // Q fragment (B-operand): col=q=l32, k(hd)=hi*8+j
    const int qrow = q0 + w * 32 + l32;
    v8h qf = *(const v8h*)(Qr + ((size_t)bh * NN + qrow) * 16 + hi * 8);

    // ones rows of both Ve buffers (rows 16-31), written once
    {
        v8h one8;
        #pragma unroll
        for (int i = 0; i < 8; ++i) one8[i] = (_Float16)1.f;
        int rr = 16 + (tid >> 4), cc = (tid & 15) * 8;
        *(v8h*)((_Float16*)(smem +         6144) + rr * 136 + cc) = one8;
        *(v8h*)((_Float16*)(smem + 15360 + 6144) + rr * 136 + cc) = one8;
    }

    v16f acc = zero16();

    const int krow = tid >> 1, kpar = tid & 1;   // K staging: 128 rows x 2 halves
    const int vhd = tid >> 4, vg = tid & 15;     // V staging: 16 hd x 16 k-groups of 8
    const _Float16* Kbase = Kr + (size_t)bh * NN * 16;
    const _Float16* Vbase = VT + ((size_t)bh * 16 + vhd) * NN;
    const unsigned char* mbase = mask + b * NN;

    // ---- prologue: prefetch tile 0 into registers ----
    v8h kv = *(const v8h*)(Kbase + (size_t)krow * 16 + kpar * 8);
    v8h vv = *(const v8h*)(Vbase + vg * 8);
    float adv = 0.f;
    if (tid < 128) adv = mbase[tid] ? -1e30f : C1F;

    for (int it = 0; it < 16; ++it) {
        char* buf = smem + (it & 1) * 15360;
        _Float16* Kt = (_Float16*)buf;           // [128][24] halfs
        _Float16* Ve = (_Float16*)(buf + 6144);  // [32][136] halfs
        float*    av = (float*)(buf + 14848);    // [128]

        // ---- stage current tile from regs (buffer vacated at barrier it-1) ----
        *(v8h*)(Kt + krow * 24 + kpar * 8) = kv;
        {
            _Float16* vb = Ve + vhd * 136 + (vg >> 1) * 16 + (vg & 1) * 4;
            v4h lo4, hi4;
            lo4[0]=vv[0]; lo4[1]=vv[1]; lo4[2]=vv[2]; lo4[3]=vv[3];
            hi4[0]=vv[4]; hi4[1]=vv[5]; hi4[2]=vv[6]; hi4[3]=vv[7];
            *(v4h*)(vb)     = lo4;     // logical k g*8+0..3
            *(v4h*)(vb + 8) = hi4;     // logical k g*8+4..7 -> swapped slot group
        }
        if (tid < 128) av[tid] = adv;
        // ---- issue next tile's global loads (latency hides under compute) ----
        if (it < 15) {
            const int k0n = (it + 1) * 128;
            kv = *(const v8h*)(Kbase + (size_t)(k0n + krow) * 16 + kpar * 8);
            vv = *(const v8h*)(Vbase + k0n + vg * 8);
            if (tid < 128) adv = mbase[k0n + tid] ? -1e30f : C1F;
        }
        __syncthreads();                         // staging visible; only barrier/iter

        #pragma unroll
        for (int kc = 0; kc < 4; ++kc) {
            // A = K rows (row=k-pos=l32 within chunk, k-dim=hd=hi*8+j)
            v8h kf = *(const v8h*)(Kt + (kc * 32 + l32) * 24 + hi * 8);
            v16f sv = mfma32(kf, qf, zero16());   // S^T: col=q=l32, row k=(r&3)+8*(r>>2)+4*hi

            v4f ad[4];
            #pragma unroll
            for (int gg = 0; gg < 4; ++gg)
                ad[gg] = *(const v4f*)(av + kc * 32 + gg * 8 + hi * 4);

            float p[16];
            #pragma unroll
            for (int r = 0; r < 16; ++r) {
                float u  = fexp2(sv[r]);                           // e^{2z}
                float rc = __builtin_amdgcn_rcpf(u + 1.f);         // inf-safe
                p[r] = fexp2(__builtin_fmaf(rc, -C2F, ad[r >> 2][r & 3]));
            }

            #pragma unroll
            for (int c2 = 0; c2 < 2; ++c2) {
                v8h pa;
                #pragma unroll
                for (int j = 0; j < 8; ++j) pa[j] = (_Float16)p[c2 * 8 + j];
                v8h vf = *(const v8h*)(Ve + l32 * 136 + (kc * 2 + c2) * 16 + hi * 8);
                acc = mfma32(pa, vf, acc);         // rows=q, cols: 0-15 O^T, 16-31 rowsum
            }
        }
    }

    // ---- epilogue (no barrier: writes buf0 Kt area; last compute used buf1) ----
    float rs[16];
    #pragma unroll
    for (int r = 0; r < 16; ++r) rs[r] = __shfl_xor(acc[r], 16, 64);

    _Float16* myOt = (_Float16*)smem + w * 768;        // per-wave [32 q][24] halfs in buf0
    if (!(lane & 16)) {                                // lanes holding O columns
        int j = lane & 15;                             // hd
        #pragma unroll
        for (int r = 0; r < 16; ++r) {
            int qr = (r & 3) + 8 * (r >> 2) + 4 * hi;  // q-row within wave tile
            myOt[qr * 24 + j] = (_Float16)(acc[r] * __builtin_amdgcn_rcpf(rs[r]));
        }
    }
    asm volatile("s_waitcnt lgkmcnt(0)" ::: "memory"); // wave-private region
    v8h ov = *(const v8h*)(myOt + (lane >> 1) * 24 + (lane & 1) * 8);
    *(v8h*)(Obuf + ((size_t)(b * NN + q0 + w * 32 + (lane >> 1)) * 128) + h * 16 + (lane & 1) * 8) = ov;
}

// ---------------- output projection: out = O @ Wout^T (fp32 out), col-split grid.y ----------------
// Wo read as fp32 + inline cvt (WoH/prep eliminated).
__global__ __launch_bounds__(256) void outproj_kernel(
    const _Float16* __restrict__ Obuf, const float* __restrict__ Wo,
    float* __restrict__ out)
{
    __shared__ __align__(16) _Float16 ob[64][136];
    const int tid = threadIdx.x;
    const int r0 = blockIdx.x * 64;
    const int ct0 = blockIdx.y * 2;                 // 4-way col split: 32 cols/block
    #pragma unroll
    for (int i = 0; i < 8; ++i) {
        int u = tid + i * 256;
        int row = u >> 5, c4 = (u & 31) * 4;
        *(v4h*)&ob[row][c4] = *(const v4h*)(Obuf + (size_t)(r0 + row) * 128 + c4);
    }
    __syncthreads();
    const int w = tid >> 6, lane = tid & 63;
    const int l16 = lane & 15, quad = lane >> 4;
    v4h af[8];
    #pragma unroll
    for (int kt = 0; kt < 8; ++kt)
        af[kt] = *(const v4h*)&ob[w * 16 + l16][kt * 16 + quad * 4];
    v4f acc[2];
    #pragma unroll
    for (int c = 0; c < 2; ++c) acc[c] = zero4();
    #pragma unroll
    for (int kt = 0; kt < 8; ++kt)
        #pragma unroll
        for (int c = 0; c < 2; ++c) {
            v4f wv = *(const v4f*)(Wo + ((ct0 + c) * 16 + l16) * 128 + kt * 16 + quad * 4);
            v4h wf; wf[0]=(_Float16)wv[0]; wf[1]=(_Float16)wv[1]; wf[2]=(_Float16)wv[2]; wf[3]=(_Float16)wv[3];
            acc[c] = mfma16(af[kt], wf, acc[c]);
        }
    #pragma unroll
    for (int c = 0; c < 2; ++c)
        #pragma unroll
        for (int r = 0; r < 4; ++r)
            out[(size_t)(r0 + w * 16 + quad * 4 + r) * 128 + (ct0 + c) * 16 + l16] = acc[c][r];
}

extern "C" void kernel_launch(void* const* d_in, const int* in_sizes, int n_in,
                              void* d_out, int out_size, void* d_ws, size_t ws_size,
                              hipStream_t stream)
{
    const float* q  = (const float*)d_in[0];
    const float* k  = (const float*)d_in[1];
    const float* v  = (const float*)d_in[2];
    const float* Wq = (const float*)d_in[3];
    const float* Wk = (const float*)d_in[4];
    const float* Wv = (const float*)d_in[5];
    const float* Wo = (const float*)d_in[6];
    const unsigned char* mask = (const unsigned char*)d_in[7];
    float* out = (float*)d_out;

    char* ws = (char*)d_ws;
    _Float16* Qr   = (_Float16*)(ws);                 //   4 MB  (B,H,N,16)
    _Float16* Kr   = (_Float16*)(ws + 4194304);       //   4 MB
    _Float16* VTd  = (_Float16*)(ws + 8388608);       //   4 MB  (B,H,16,N)
    _Float16* Obuf = (_Float16*)(ws + 12582912);      //   4 MB  (B*N,128)

    proj_rope_kernel<<<dim3(256, 3), 256, 0, stream>>>(q, k, v, Wq, Wk, Wv, Qr, Kr, VTd);
    attn_kernel<<<1024, 256, 0, stream>>>(Qr, Kr, VTd, mask, Obuf);
    outproj_kernel<<<dim3(256, 4), 256, 0, stream>>>(Obuf, Wo, out);
}